// Round 6
// baseline (336.555 us; speedup 1.0000x reference)
//
#include <hip/hip_runtime.h>

// ---------------------------------------------------------------------------
// AGNN: h = relu(x@W1^T+b1); 4x [ h = relu(agnn(h)) ]; out = h@W2^T+b2
// N=100000, E=1600000, IN=128, HID=OUT=64, float32 in/out.
// Between layers: xn = h/(||h||+eps) bf16 (128 B/row) + nrm f32.
// agnn: 2 nodes/wave, 4 edge-groups x 8 lanes, 4 edges in flight per group,
//       dot-reduce via DPP row_shr adds + single ds_swizzle broadcast.
// gemm1: 64-node blocks, K staged in two 64-chunks (32 KiB LDS -> 5 blk/CU).
// ---------------------------------------------------------------------------

typedef float v2f __attribute__((ext_vector_type(2)));

#define DEV_INLINE __device__ __forceinline__

DEV_INLINE v2f bf2(unsigned u) {
    v2f r;
    r.x = __uint_as_float(u << 16);
    r.y = __uint_as_float(u & 0xffff0000u);
    return r;
}

DEV_INLINE unsigned pack_bf16_2(float a, float b) {   // RNE, no NaN here
    unsigned ua = __float_as_uint(a); ua += 0x7fffu + ((ua >> 16) & 1u);
    unsigned ub = __float_as_uint(b); ub += 0x7fffu + ((ub >> 16) & 1u);
    return (ua >> 16) | (ub & 0xffff0000u);
}

// sum v across each aligned 8-lane group; result valid in lane 7 (mod 8)
// of each group, then broadcast to all 8 via ds_swizzle (lane->(lane&0x18)|7).
template <int CTRL>
DEV_INLINE float dpp_add(float v) {
    int sh = __builtin_amdgcn_update_dpp(0, __float_as_int(v), CTRL, 0xF, 0xF, true);
    return v + __int_as_float(sh);
}
DEV_INLINE float group8_sum_bcast(float v) {
    float r = dpp_add<0x111>(v);   // row_shr:1
    r = dpp_add<0x112>(r);         // row_shr:2
    r = dpp_add<0x114>(r);         // row_shr:4  -> lane 7 (mod 8) has sum
    return __int_as_float(__builtin_amdgcn_ds_swizzle(__float_as_int(r), 0x00F8));
}

__global__ __launch_bounds__(256) void build_rowptr(const int* __restrict__ row,
                                                    int* __restrict__ ptr,
                                                    int N, int E) {
    int i = blockIdx.x * blockDim.x + threadIdx.x;
    if (i > N) return;
    int lo = 0, hi = E;
    while (lo < hi) {
        int mid = (lo + hi) >> 1;
        if (row[mid] < i) lo = mid + 1; else hi = mid;
    }
    ptr[i] = lo;
}

// r = relu(x[i,:128]@W1^T + b1); xn[i]=bf16(r/(||r||+eps)); nrm[i]=||r||+eps
// K staged in two 64-wide chunks -> 32 KiB LDS -> 5 blocks/CU.
__global__ __launch_bounds__(256) void gemm1_relu(const float* __restrict__ x,
                                                  const float* __restrict__ W1,
                                                  const float* __restrict__ b1,
                                                  unsigned short* __restrict__ xn,
                                                  float* __restrict__ nrm,
                                                  int N) {
    __shared__ __align__(16) float Wt[64 * 64];   // Wt[k*64+o], k in chunk
    __shared__ __align__(16) float xT[64 * 64];   // xT[k*64+m]
    const int tid  = threadIdx.x;
    const int tx   = tid & 15;
    const int ty   = tid >> 4;
    const int base = blockIdx.x * 64;

    float4 b4 = ((const float4*)b1)[tx];
    float4 acc[4];
    acc[0] = b4; acc[1] = b4; acc[2] = b4; acc[3] = b4;

    for (int kc = 0; kc < 128; kc += 64) {
        if (kc) __syncthreads();              // protect LDS before overwrite
        const float4* W4 = (const float4*)W1;
        for (int idx = tid; idx < 64 * 16; idx += 256) {
            int o = idx & 63, k4 = idx >> 6;          // k4 in [0,16)
            float4 v = W4[o * 32 + (kc >> 2) + k4];
            Wt[(4 * k4 + 0) * 64 + o] = v.x;
            Wt[(4 * k4 + 1) * 64 + o] = v.y;
            Wt[(4 * k4 + 2) * 64 + o] = v.z;
            Wt[(4 * k4 + 3) * 64 + o] = v.w;
        }
        const float4* x4p = (const float4*)x;
        for (int idx = tid; idx < 64 * 16; idx += 256) {
            int mm = idx & 63, k4 = idx >> 6;
            int node = base + mm;
            float4 v = make_float4(0.f, 0.f, 0.f, 0.f);
            if (node < N) v = x4p[(size_t)node * 32 + (kc >> 2) + k4];
            xT[(4 * k4 + 0) * 64 + mm] = v.x;
            xT[(4 * k4 + 1) * 64 + mm] = v.y;
            xT[(4 * k4 + 2) * 64 + mm] = v.z;
            xT[(4 * k4 + 3) * 64 + mm] = v.w;
        }
        __syncthreads();

#pragma unroll 4
        for (int k = 0; k < 64; ++k) {
            const float4 w4 = *(const float4*)&Wt[k * 64 + 4 * tx];
            const float4 xv = *(const float4*)&xT[k * 64 + 4 * ty];
            acc[0].x = fmaf(xv.x, w4.x, acc[0].x);
            acc[0].y = fmaf(xv.x, w4.y, acc[0].y);
            acc[0].z = fmaf(xv.x, w4.z, acc[0].z);
            acc[0].w = fmaf(xv.x, w4.w, acc[0].w);
            acc[1].x = fmaf(xv.y, w4.x, acc[1].x);
            acc[1].y = fmaf(xv.y, w4.y, acc[1].y);
            acc[1].z = fmaf(xv.y, w4.z, acc[1].z);
            acc[1].w = fmaf(xv.y, w4.w, acc[1].w);
            acc[2].x = fmaf(xv.z, w4.x, acc[2].x);
            acc[2].y = fmaf(xv.z, w4.y, acc[2].y);
            acc[2].z = fmaf(xv.z, w4.z, acc[2].z);
            acc[2].w = fmaf(xv.z, w4.w, acc[2].w);
            acc[3].x = fmaf(xv.w, w4.x, acc[3].x);
            acc[3].y = fmaf(xv.w, w4.y, acc[3].y);
            acc[3].z = fmaf(xv.w, w4.z, acc[3].z);
            acc[3].w = fmaf(xv.w, w4.w, acc[3].w);
        }
    }

#pragma unroll
    for (int mm = 0; mm < 4; ++mm) {
        float4 r = acc[mm];
        r.x = fmaxf(r.x, 0.f); r.y = fmaxf(r.y, 0.f);
        r.z = fmaxf(r.z, 0.f); r.w = fmaxf(r.w, 0.f);
        float s = fmaf(r.x, r.x, fmaf(r.y, r.y, fmaf(r.z, r.z, r.w * r.w)));
        s += __shfl_xor(s, 1, 64);
        s += __shfl_xor(s, 2, 64);
        s += __shfl_xor(s, 4, 64);
        s += __shfl_xor(s, 8, 64);               // butterfly: all tx have sum
        const float nn  = sqrtf(s) + 1e-12f;
        const float inv = 1.f / nn;
        int node = base + 4 * ty + mm;
        if (node < N) {
            uint2 pk;
            pk.x = pack_bf16_2(r.x * inv, r.y * inv);
            pk.y = pack_bf16_2(r.z * inv, r.w * inv);
            *(uint2*)&xn[(size_t)node * 64 + 4 * tx] = pk;
            if (tx == mm) nrm[node] = nn;
        }
    }
}

// 2 nodes per wave; 4 edge-groups x 8 lanes; 4 edges in flight per group.
__global__ __launch_bounds__(256) void agnn_layer(const uint4* __restrict__ xn4,
                                                  const float* __restrict__ nrm,
                                                  const int* __restrict__ ptr,
                                                  const int* __restrict__ col,
                                                  uint4* __restrict__ xo4,
                                                  float* __restrict__ nrmo,
                                                  int N) {
    const int tid  = threadIdx.x;
    const int lane = tid & 63;
    const int g    = (lane >> 3) & 3;   // edge group 0..3 within 32-lane half
    const int sub  = lane & 7;          // 16B chunk of the 128B row
    const int i    = blockIdx.x * 8 + (tid >> 5);
    if (i >= N) return;

    const float L2E = 1.4426950408889634f;
    const uint4 hv = xn4[(size_t)i * 8 + sub];
    v2f hi0 = bf2(hv.x), hi1 = bf2(hv.y), hi2v = bf2(hv.z), hi3 = bf2(hv.w);
    hi0 *= L2E; hi1 *= L2E; hi2v *= L2E; hi3 *= L2E;   // p = exp2(dot)

    const int p0 = ptr[i], p1 = ptr[i + 1];

    float den = 0.f;
    v2f a0 = {0.f, 0.f}, a1 = {0.f, 0.f}, a2 = {0.f, 0.f}, a3 = {0.f, 0.f};

#define EDGE_BODY(V, NRMJ)                                                   \
    {                                                                        \
        v2f x0 = bf2((V).x), x1 = bf2((V).y), x2 = bf2((V).z), x3 = bf2((V).w); \
        v2f s2v = hi0 * x0; s2v += hi1 * x1; s2v += hi2v * x2; s2v += hi3 * x3; \
        const float p = exp2f(group8_sum_bcast(s2v.x + s2v.y));              \
        den += p;                                                            \
        const float wp = p * (NRMJ);                                         \
        v2f w2 = {wp, wp};                                                   \
        a0 += w2 * x0; a1 += w2 * x1; a2 += w2 * x2; a3 += w2 * x3;          \
    }

    int e = p0 + g;
    for (; e + 12 < p1; e += 16) {       // 4 edges per group in flight
        const int j0 = col[e];
        const int j1 = col[e + 4];
        const int j2 = col[e + 8];
        const int j3 = col[e + 12];
        const uint4 v0 = xn4[(size_t)j0 * 8 + sub];
        const uint4 v1 = xn4[(size_t)j1 * 8 + sub];
        const uint4 v2 = xn4[(size_t)j2 * 8 + sub];
        const uint4 v3 = xn4[(size_t)j3 * 8 + sub];
        const float n0 = nrm[j0];
        const float n1 = nrm[j1];
        const float n2 = nrm[j2];
        const float n3 = nrm[j3];
        EDGE_BODY(v0, n0)
        EDGE_BODY(v1, n1)
        EDGE_BODY(v2, n2)
        EDGE_BODY(v3, n3)
    }
    for (; e < p1; e += 4) {
        const int j = col[e];
        const uint4 v = xn4[(size_t)j * 8 + sub];
        const float nj = nrm[j];
        EDGE_BODY(v, nj)
    }
#undef EDGE_BODY

    // merge the 4 edge-groups (within the 32-lane half): xor 8, xor 16
#pragma unroll
    for (int off = 8; off <= 16; off <<= 1) {
        den  += __shfl_xor(den, off, 64);
        a0.x += __shfl_xor(a0.x, off, 64);  a0.y += __shfl_xor(a0.y, off, 64);
        a1.x += __shfl_xor(a1.x, off, 64);  a1.y += __shfl_xor(a1.y, off, 64);
        a2.x += __shfl_xor(a2.x, off, 64);  a2.y += __shfl_xor(a2.y, off, 64);
        a3.x += __shfl_xor(a3.x, off, 64);  a3.y += __shfl_xor(a3.y, off, 64);
    }

    const float id = 1.f / fmaxf(den, 1e-12f);
    float o[8];
    o[0] = fmaxf(a0.x * id, 0.f); o[1] = fmaxf(a0.y * id, 0.f);
    o[2] = fmaxf(a1.x * id, 0.f); o[3] = fmaxf(a1.y * id, 0.f);
    o[4] = fmaxf(a2.x * id, 0.f); o[5] = fmaxf(a2.y * id, 0.f);
    o[6] = fmaxf(a3.x * id, 0.f); o[7] = fmaxf(a3.y * id, 0.f);

    float s2 = 0.f;
#pragma unroll
    for (int t = 0; t < 8; ++t) s2 = fmaf(o[t], o[t], s2);
    s2 += __shfl_xor(s2, 1, 64);
    s2 += __shfl_xor(s2, 2, 64);
    s2 += __shfl_xor(s2, 4, 64);
    const float nn  = sqrtf(s2) + 1e-12f;
    const float inv = 1.f / nn;

    if (g == 0) {
        uint4 ov;
        ov.x = pack_bf16_2(o[0] * inv, o[1] * inv);
        ov.y = pack_bf16_2(o[2] * inv, o[3] * inv);
        ov.z = pack_bf16_2(o[4] * inv, o[5] * inv);
        ov.w = pack_bf16_2(o[6] * inv, o[7] * inv);
        xo4[(size_t)i * 8 + sub] = ov;
        if (sub == 0) nrmo[i] = nn;
    }
}

// out[i,:64] = (xn[i]*nrm[i]) @ W2^T + b2   (f32 out)
__global__ __launch_bounds__(256) void gemm2(const unsigned short* __restrict__ xn,
                                             const float* __restrict__ nrm,
                                             const float* __restrict__ W2,
                                             const float* __restrict__ b2,
                                             float* __restrict__ out,
                                             int N) {
    __shared__ __align__(16) float Wt[64 * 64];
    __shared__ __align__(16) float xT[64 * 64];
    const int tid  = threadIdx.x;
    const int tx   = tid & 15;
    const int ty   = tid >> 4;
    const int base = blockIdx.x * 64;

    {
        const float4* W4 = (const float4*)W2;
        for (int idx = tid; idx < 64 * 16; idx += 256) {
            int o = idx & 63, k4 = idx >> 6;
            float4 v = W4[o * 16 + k4];
            Wt[(4 * k4 + 0) * 64 + o] = v.x;
            Wt[(4 * k4 + 1) * 64 + o] = v.y;
            Wt[(4 * k4 + 2) * 64 + o] = v.z;
            Wt[(4 * k4 + 3) * 64 + o] = v.w;
        }
        const uint2* x2 = (const uint2*)xn;
        for (int idx = tid; idx < 64 * 16; idx += 256) {
            int mm = idx & 63, k4 = idx >> 6;
            int node = base + mm;
            uint2 v = make_uint2(0u, 0u);
            float nn = 0.f;
            if (node < N) { v = x2[(size_t)node * 16 + k4]; nn = nrm[node]; }
            xT[(4 * k4 + 0) * 64 + mm] = __uint_as_float(v.x << 16) * nn;
            xT[(4 * k4 + 1) * 64 + mm] = __uint_as_float(v.x & 0xffff0000u) * nn;
            xT[(4 * k4 + 2) * 64 + mm] = __uint_as_float(v.y << 16) * nn;
            xT[(4 * k4 + 3) * 64 + mm] = __uint_as_float(v.y & 0xffff0000u) * nn;
        }
    }
    __syncthreads();

    float4 b4 = ((const float4*)b2)[tx];
    float4 acc[4];
    acc[0] = b4; acc[1] = b4; acc[2] = b4; acc[3] = b4;

#pragma unroll 4
    for (int k = 0; k < 64; ++k) {
        const float4 w4 = *(const float4*)&Wt[k * 64 + 4 * tx];
        const float4 xv = *(const float4*)&xT[k * 64 + 4 * ty];
        acc[0].x = fmaf(xv.x, w4.x, acc[0].x);
        acc[0].y = fmaf(xv.x, w4.y, acc[0].y);
        acc[0].z = fmaf(xv.x, w4.z, acc[0].z);
        acc[0].w = fmaf(xv.x, w4.w, acc[0].w);
        acc[1].x = fmaf(xv.y, w4.x, acc[1].x);
        acc[1].y = fmaf(xv.y, w4.y, acc[1].y);
        acc[1].z = fmaf(xv.y, w4.z, acc[1].z);
        acc[1].w = fmaf(xv.y, w4.w, acc[1].w);
        acc[2].x = fmaf(xv.z, w4.x, acc[2].x);
        acc[2].y = fmaf(xv.z, w4.y, acc[2].y);
        acc[2].z = fmaf(xv.z, w4.z, acc[2].z);
        acc[2].w = fmaf(xv.z, w4.w, acc[2].w);
        acc[3].x = fmaf(xv.w, w4.x, acc[3].x);
        acc[3].y = fmaf(xv.w, w4.y, acc[3].y);
        acc[3].z = fmaf(xv.w, w4.z, acc[3].z);
        acc[3].w = fmaf(xv.w, w4.w, acc[3].w);
    }

#pragma unroll
    for (int mm = 0; mm < 4; ++mm) {
        int node = base + 4 * ty + mm;
        if (node < N) *(float4*)&out[(size_t)node * 64 + 4 * tx] = acc[mm];
    }
}

extern "C" void kernel_launch(void* const* d_in, const int* in_sizes, int n_in,
                              void* d_out, int out_size, void* d_ws, size_t ws_size,
                              hipStream_t stream) {
    const float* x   = (const float*)d_in[0];
    const int*   row = (const int*)d_in[1];
    const int*   col = (const int*)d_in[2];
    const float* W1  = (const float*)d_in[3];
    const float* b1  = (const float*)d_in[4];
    const float* W2  = (const float*)d_in[5];
    const float* b2  = (const float*)d_in[6];
    float* out = (float*)d_out;

    const int N = in_sizes[0] / 128;
    const int E = in_sizes[1];

    char* ws = (char*)d_ws;
    size_t off = 0;
    unsigned short* ha = (unsigned short*)(ws + off); off += (size_t)N * 64 * 2;
    unsigned short* hb = (unsigned short*)(ws + off); off += (size_t)N * 64 * 2;
    float* na_ = (float*)(ws + off); off += (size_t)N * sizeof(float);
    float* nb_ = (float*)(ws + off); off += (size_t)N * sizeof(float);
    int*   ptr = (int*)  (ws + off); off += (size_t)(N + 1) * sizeof(int);
    (void)ws_size; (void)n_in; (void)out_size;

    build_rowptr<<<(N + 256) / 256, 256, 0, stream>>>(row, ptr, N, E);

    const int nbG = (N + 63) / 64;
    gemm1_relu<<<nbG, 256, 0, stream>>>(x, W1, b1, ha, na_, N);

    const int nb8 = (N + 7) / 8;
    unsigned short* hc = ha; unsigned short* hn = hb;
    float* nc = na_; float* nn = nb_;
    for (int l = 0; l < 4; ++l) {
        agnn_layer<<<nb8, 256, 0, stream>>>((const uint4*)hc, nc, ptr, col,
                                            (uint4*)hn, nn, N);
        unsigned short* t = hc; hc = hn; hn = t;
        float* tf = nc; nc = nn; nn = tf;
    }

    gemm2<<<nbG, 256, 0, stream>>>(hc, nc, W2, b2, out, N);
}

// Round 7
// 306.122 us; speedup vs baseline: 1.0994x; 1.0994x over previous
//
#include <hip/hip_runtime.h>

// ---------------------------------------------------------------------------
// AGNN: h = relu(x@W1^T+b1); 4x [ h = relu(agnn(h)) ]; out = h@W2^T+b2
// N=100000, E=1600000, IN=128, HID=OUT=64, float32 in/out.
// Between layers: xn = h/(||h||+eps) stored FP16 (128 B/row) + nrm f32.
//   p = exp2( dot(xn_i * log2e, xn_j) );  out_i = sum p * nrm_j * xn_j / sum p
// agnn: 2 nodes/wave, 4 edge-groups x 8 lanes, 2 edges in flight per group.
//   dot  : v_dot2_f32_f16 on raw loaded registers (no unpack)
//   accum: v_pk_fma_f16 on raw loaded registers (no unpack)
// gemm1: 64-node blocks, K staged in two 64-chunks (32 KiB LDS -> 5 blk/CU).
// ---------------------------------------------------------------------------

typedef _Float16 h2 __attribute__((ext_vector_type(2)));

union U4H { uint4 u; h2 h[4]; };
union U2H { uint2 u; h2 h[2]; };
union UHI { unsigned u; h2 h; };

#define DEV_INLINE __device__ __forceinline__

DEV_INLINE h2 mkh2(float a, float b) {
    h2 r; r.x = (_Float16)a; r.y = (_Float16)b; return r;
}

__global__ __launch_bounds__(256) void build_rowptr(const int* __restrict__ row,
                                                    int* __restrict__ ptr,
                                                    int N, int E) {
    int i = blockIdx.x * blockDim.x + threadIdx.x;
    if (i > N) return;
    int lo = 0, hi = E;
    while (lo < hi) {
        int mid = (lo + hi) >> 1;
        if (row[mid] < i) lo = mid + 1; else hi = mid;
    }
    ptr[i] = lo;
}

// r = relu(x[i,:128]@W1^T + b1); xn[i]=f16(r/(||r||+eps)); nrm[i]=||r||+eps
__global__ __launch_bounds__(256) void gemm1_relu(const float* __restrict__ x,
                                                  const float* __restrict__ W1,
                                                  const float* __restrict__ b1,
                                                  unsigned short* __restrict__ xn,
                                                  float* __restrict__ nrm,
                                                  int N) {
    __shared__ __align__(16) float Wt[64 * 64];   // Wt[k*64+o], k in chunk
    __shared__ __align__(16) float xT[64 * 64];   // xT[k*64+m]
    const int tid  = threadIdx.x;
    const int tx   = tid & 15;
    const int ty   = tid >> 4;
    const int base = blockIdx.x * 64;

    float4 b4 = ((const float4*)b1)[tx];
    float4 acc[4];
    acc[0] = b4; acc[1] = b4; acc[2] = b4; acc[3] = b4;

    for (int kc = 0; kc < 128; kc += 64) {
        if (kc) __syncthreads();
        const float4* W4 = (const float4*)W1;
        for (int idx = tid; idx < 64 * 16; idx += 256) {
            int o = idx & 63, k4 = idx >> 6;
            float4 v = W4[o * 32 + (kc >> 2) + k4];
            Wt[(4 * k4 + 0) * 64 + o] = v.x;
            Wt[(4 * k4 + 1) * 64 + o] = v.y;
            Wt[(4 * k4 + 2) * 64 + o] = v.z;
            Wt[(4 * k4 + 3) * 64 + o] = v.w;
        }
        const float4* x4p = (const float4*)x;
        for (int idx = tid; idx < 64 * 16; idx += 256) {
            int mm = idx & 63, k4 = idx >> 6;
            int node = base + mm;
            float4 v = make_float4(0.f, 0.f, 0.f, 0.f);
            if (node < N) v = x4p[(size_t)node * 32 + (kc >> 2) + k4];
            xT[(4 * k4 + 0) * 64 + mm] = v.x;
            xT[(4 * k4 + 1) * 64 + mm] = v.y;
            xT[(4 * k4 + 2) * 64 + mm] = v.z;
            xT[(4 * k4 + 3) * 64 + mm] = v.w;
        }
        __syncthreads();

#pragma unroll 4
        for (int k = 0; k < 64; ++k) {
            const float4 w4 = *(const float4*)&Wt[k * 64 + 4 * tx];
            const float4 xv = *(const float4*)&xT[k * 64 + 4 * ty];
            acc[0].x = fmaf(xv.x, w4.x, acc[0].x);
            acc[0].y = fmaf(xv.x, w4.y, acc[0].y);
            acc[0].z = fmaf(xv.x, w4.z, acc[0].z);
            acc[0].w = fmaf(xv.x, w4.w, acc[0].w);
            acc[1].x = fmaf(xv.y, w4.x, acc[1].x);
            acc[1].y = fmaf(xv.y, w4.y, acc[1].y);
            acc[1].z = fmaf(xv.y, w4.z, acc[1].z);
            acc[1].w = fmaf(xv.y, w4.w, acc[1].w);
            acc[2].x = fmaf(xv.z, w4.x, acc[2].x);
            acc[2].y = fmaf(xv.z, w4.y, acc[2].y);
            acc[2].z = fmaf(xv.z, w4.z, acc[2].z);
            acc[2].w = fmaf(xv.z, w4.w, acc[2].w);
            acc[3].x = fmaf(xv.w, w4.x, acc[3].x);
            acc[3].y = fmaf(xv.w, w4.y, acc[3].y);
            acc[3].z = fmaf(xv.w, w4.z, acc[3].z);
            acc[3].w = fmaf(xv.w, w4.w, acc[3].w);
        }
    }

#pragma unroll
    for (int mm = 0; mm < 4; ++mm) {
        float4 r = acc[mm];
        r.x = fmaxf(r.x, 0.f); r.y = fmaxf(r.y, 0.f);
        r.z = fmaxf(r.z, 0.f); r.w = fmaxf(r.w, 0.f);
        float s = fmaf(r.x, r.x, fmaf(r.y, r.y, fmaf(r.z, r.z, r.w * r.w)));
        s += __shfl_xor(s, 1, 64);
        s += __shfl_xor(s, 2, 64);
        s += __shfl_xor(s, 4, 64);
        s += __shfl_xor(s, 8, 64);
        const float nn  = sqrtf(s) + 1e-12f;
        const float inv = 1.f / nn;
        int node = base + 4 * ty + mm;
        if (node < N) {
            U2H pk;
            pk.h[0] = mkh2(r.x * inv, r.y * inv);
            pk.h[1] = mkh2(r.z * inv, r.w * inv);
            *(uint2*)&xn[(size_t)node * 64 + 4 * tx] = pk.u;
            if (tx == mm) nrm[node] = nn;
        }
    }
}

// 2 nodes per wave; 4 edge-groups x 8 lanes; 2 edges in flight per group.
__global__ __launch_bounds__(256) void agnn_layer(const uint4* __restrict__ xn4,
                                                  const float* __restrict__ nrm,
                                                  const int* __restrict__ ptr,
                                                  const int* __restrict__ col,
                                                  uint4* __restrict__ xo4,
                                                  float* __restrict__ nrmo,
                                                  int N) {
    const int tid  = threadIdx.x;
    const int lane = tid & 63;
    const int g    = (lane >> 3) & 3;   // edge group 0..3 within 32-lane half
    const int sub  = lane & 7;          // 16B chunk of the 128B row
    const int i    = blockIdx.x * 8 + (tid >> 5);
    if (i >= N) return;

    U4H hi_;
    hi_.u = xn4[(unsigned)i * 8u + sub];
    {
        const _Float16 L2E = (_Float16)1.4426950408889634f;
        h2 l2 = {L2E, L2E};
#pragma unroll
        for (int t = 0; t < 4; ++t) hi_.h[t] *= l2;   // p = exp2(dot)
    }

    const int p0 = ptr[i], p1 = ptr[i + 1];

    float den = 0.f;
    U4H acc;
    acc.h[0] = mkh2(0.f, 0.f); acc.h[1] = mkh2(0.f, 0.f);
    acc.h[2] = mkh2(0.f, 0.f); acc.h[3] = mkh2(0.f, 0.f);

#define EDGE_BODY(VU, NRMJ)                                                  \
    {                                                                        \
        U4H xa; xa.u = (VU);                                                 \
        float s = 0.f;                                                       \
        s = __builtin_amdgcn_fdot2(hi_.h[0], xa.h[0], s, false);             \
        s = __builtin_amdgcn_fdot2(hi_.h[1], xa.h[1], s, false);             \
        s = __builtin_amdgcn_fdot2(hi_.h[2], xa.h[2], s, false);             \
        s = __builtin_amdgcn_fdot2(hi_.h[3], xa.h[3], s, false);             \
        s += __shfl_xor(s, 1, 64);                                           \
        s += __shfl_xor(s, 2, 64);                                           \
        s += __shfl_xor(s, 4, 64);                                           \
        const float p = exp2f(s);                                            \
        den += p;                                                            \
        const _Float16 wh = (_Float16)(p * (NRMJ));                          \
        h2 w2 = {wh, wh};                                                    \
        acc.h[0] += w2 * xa.h[0];                                            \
        acc.h[1] += w2 * xa.h[1];                                            \
        acc.h[2] += w2 * xa.h[2];                                            \
        acc.h[3] += w2 * xa.h[3];                                            \
    }

    int e = p0 + g;
    for (; e + 4 < p1; e += 8) {          // 2 edges per group in flight
        const int ja = col[e];
        const int jb = col[e + 4];
        const uint4 va = xn4[(unsigned)ja * 8u + sub];
        const uint4 vb = xn4[(unsigned)jb * 8u + sub];
        const float na = nrm[ja];
        const float nb = nrm[jb];
        EDGE_BODY(va, na)
        EDGE_BODY(vb, nb)
    }
    if (e < p1) {
        const int j = col[e];
        const uint4 v = xn4[(unsigned)j * 8u + sub];
        const float nj = nrm[j];
        EDGE_BODY(v, nj)
    }
#undef EDGE_BODY

    // merge the 4 edge-groups (within the 32-lane half): xor 8, xor 16
#pragma unroll
    for (int off = 8; off <= 16; off <<= 1) {
        den += __shfl_xor(den, off, 64);
#pragma unroll
        for (int t = 0; t < 4; ++t) {
            UHI a; a.h = acc.h[t];
            UHI b; b.u = (unsigned)__shfl_xor((int)a.u, off, 64);
            acc.h[t] = a.h + b.h;
        }
    }

    const float id = 1.f / fmaxf(den, 1e-12f);
    float o[8];
#pragma unroll
    for (int t = 0; t < 4; ++t) {
        o[2 * t]     = fmaxf((float)acc.h[t].x * id, 0.f);
        o[2 * t + 1] = fmaxf((float)acc.h[t].y * id, 0.f);
    }

    float s2 = 0.f;
#pragma unroll
    for (int t = 0; t < 8; ++t) s2 = fmaf(o[t], o[t], s2);
    s2 += __shfl_xor(s2, 1, 64);
    s2 += __shfl_xor(s2, 2, 64);
    s2 += __shfl_xor(s2, 4, 64);
    const float nn  = sqrtf(s2) + 1e-12f;
    const float inv = 1.f / nn;

    if (g == 0) {
        U4H ov;
        ov.h[0] = mkh2(o[0] * inv, o[1] * inv);
        ov.h[1] = mkh2(o[2] * inv, o[3] * inv);
        ov.h[2] = mkh2(o[4] * inv, o[5] * inv);
        ov.h[3] = mkh2(o[6] * inv, o[7] * inv);
        xo4[(unsigned)i * 8u + sub] = ov.u;
        if (sub == 0) nrmo[i] = nn;
    }
}

// out[i,:64] = (xn[i]*nrm[i]) @ W2^T + b2   (f32 out)
__global__ __launch_bounds__(256) void gemm2(const unsigned short* __restrict__ xn,
                                             const float* __restrict__ nrm,
                                             const float* __restrict__ W2,
                                             const float* __restrict__ b2,
                                             float* __restrict__ out,
                                             int N) {
    __shared__ __align__(16) float Wt[64 * 64];
    __shared__ __align__(16) float xT[64 * 64];
    const int tid  = threadIdx.x;
    const int tx   = tid & 15;
    const int ty   = tid >> 4;
    const int base = blockIdx.x * 64;

    {
        const float4* W4 = (const float4*)W2;
        for (int idx = tid; idx < 64 * 16; idx += 256) {
            int o = idx & 63, k4 = idx >> 6;
            float4 v = W4[o * 16 + k4];
            Wt[(4 * k4 + 0) * 64 + o] = v.x;
            Wt[(4 * k4 + 1) * 64 + o] = v.y;
            Wt[(4 * k4 + 2) * 64 + o] = v.z;
            Wt[(4 * k4 + 3) * 64 + o] = v.w;
        }
        const uint2* x2 = (const uint2*)xn;
        for (int idx = tid; idx < 64 * 16; idx += 256) {
            int mm = idx & 63, k4 = idx >> 6;
            int node = base + mm;
            U2H v; v.u = make_uint2(0u, 0u);
            float nn = 0.f;
            if (node < N) { v.u = x2[(size_t)node * 16 + k4]; nn = nrm[node]; }
            xT[(4 * k4 + 0) * 64 + mm] = (float)v.h[0].x * nn;
            xT[(4 * k4 + 1) * 64 + mm] = (float)v.h[0].y * nn;
            xT[(4 * k4 + 2) * 64 + mm] = (float)v.h[1].x * nn;
            xT[(4 * k4 + 3) * 64 + mm] = (float)v.h[1].y * nn;
        }
    }
    __syncthreads();

    float4 b4 = ((const float4*)b2)[tx];
    float4 acc[4];
    acc[0] = b4; acc[1] = b4; acc[2] = b4; acc[3] = b4;

#pragma unroll 4
    for (int k = 0; k < 64; ++k) {
        const float4 w4 = *(const float4*)&Wt[k * 64 + 4 * tx];
        const float4 xv = *(const float4*)&xT[k * 64 + 4 * ty];
        acc[0].x = fmaf(xv.x, w4.x, acc[0].x);
        acc[0].y = fmaf(xv.x, w4.y, acc[0].y);
        acc[0].z = fmaf(xv.x, w4.z, acc[0].z);
        acc[0].w = fmaf(xv.x, w4.w, acc[0].w);
        acc[1].x = fmaf(xv.y, w4.x, acc[1].x);
        acc[1].y = fmaf(xv.y, w4.y, acc[1].y);
        acc[1].z = fmaf(xv.y, w4.z, acc[1].z);
        acc[1].w = fmaf(xv.y, w4.w, acc[1].w);
        acc[2].x = fmaf(xv.z, w4.x, acc[2].x);
        acc[2].y = fmaf(xv.z, w4.y, acc[2].y);
        acc[2].z = fmaf(xv.z, w4.z, acc[2].z);
        acc[2].w = fmaf(xv.z, w4.w, acc[2].w);
        acc[3].x = fmaf(xv.w, w4.x, acc[3].x);
        acc[3].y = fmaf(xv.w, w4.y, acc[3].y);
        acc[3].z = fmaf(xv.w, w4.z, acc[3].z);
        acc[3].w = fmaf(xv.w, w4.w, acc[3].w);
    }

#pragma unroll
    for (int mm = 0; mm < 4; ++mm) {
        int node = base + 4 * ty + mm;
        if (node < N) *(float4*)&out[(size_t)node * 64 + 4 * tx] = acc[mm];
    }
}

extern "C" void kernel_launch(void* const* d_in, const int* in_sizes, int n_in,
                              void* d_out, int out_size, void* d_ws, size_t ws_size,
                              hipStream_t stream) {
    const float* x   = (const float*)d_in[0];
    const int*   row = (const int*)d_in[1];
    const int*   col = (const int*)d_in[2];
    const float* W1  = (const float*)d_in[3];
    const float* b1  = (const float*)d_in[4];
    const float* W2  = (const float*)d_in[5];
    const float* b2  = (const float*)d_in[6];
    float* out = (float*)d_out;

    const int N = in_sizes[0] / 128;
    const int E = in_sizes[1];

    char* ws = (char*)d_ws;
    size_t off = 0;
    unsigned short* ha = (unsigned short*)(ws + off); off += (size_t)N * 64 * 2;
    unsigned short* hb = (unsigned short*)(ws + off); off += (size_t)N * 64 * 2;
    float* na_ = (float*)(ws + off); off += (size_t)N * sizeof(float);
    float* nb_ = (float*)(ws + off); off += (size_t)N * sizeof(float);
    int*   ptr = (int*)  (ws + off); off += (size_t)(N + 1) * sizeof(int);
    (void)ws_size; (void)n_in; (void)out_size;

    build_rowptr<<<(N + 256) / 256, 256, 0, stream>>>(row, ptr, N, E);

    const int nbG = (N + 63) / 64;
    gemm1_relu<<<nbG, 256, 0, stream>>>(x, W1, b1, ha, na_, N);

    const int nb8 = (N + 7) / 8;
    unsigned short* hc = ha; unsigned short* hn = hb;
    float* nc = na_; float* nn = nb_;
    for (int l = 0; l < 4; ++l) {
        agnn_layer<<<nb8, 256, 0, stream>>>((const uint4*)hc, nc, ptr, col,
                                            (uint4*)hn, nn, N);
        unsigned short* t = hc; hc = hn; hn = t;
        float* tf = nc; nc = nn; nn = tf;
    }

    gemm2<<<nbG, 256, 0, stream>>>(hc, nc, W2, b2, out, N);
}